// Round 17
// baseline (727.728 us; speedup 1.0000x reference)
//
#include <hip/hip_runtime.h>
#include <hip/hip_fp16.h>

// GCN 2-layer forward — bucket-record formulation, NO CSR. 4 launches:
//  k_histbin (261 tiles x 6144 edges): LDS hist over 782 buckets (128 nodes)
//     + shfl scan -> tileOff; scatter reg-held edges -> binned records
//     (dstLocal 7b | src 17b).
//  k_degscale (782 buckets): per-node hist over records -> dinv; fused
//     prescale Xs = f16(dinv*X).
//  k_agg_mlp_bkt (782 buckets, 512 thr, 54.4 KB LDS): 16-lane groups walk
//     record segments; broadcast 4B record, lanes atomicAdd 8B slices into
//     f32 rows[128][68] (4-bank-rotated); 8-wave 16x16x32_f16 MFMA MLP ->
//     svs = dinv*dot(relu(dD*rows@W1+b1),W2).
//  k_out_bkt (782 buckets): LDS atomicAdd p[dstLocal] += svs[src];
//     out = dD*(p+svs)+b2.

#define INF 64
#define HID 128
#define BKBITS 7
#define BKSZ 128      // nodes per bucket
#define TILE_E 6144   // edges per tile (1024 thr x 6)
#define EPT 6
#define NTMAX 264
#define RPAD 68       // padded row stride (floats): 4-bank rotation per row

using half8 = __attribute__((ext_vector_type(8))) _Float16;
using f32x4 = __attribute__((ext_vector_type(4))) float;

// Per-tile histogram + shfl scan + scatter. Extra block (bx==nt): W1t prep.
__global__ __launch_bounds__(1024) void k_histbin(const int* __restrict__ srcA,
                                                  const int* __restrict__ dstA,
                                                  int* __restrict__ tileOff,
                                                  unsigned* __restrict__ binned,
                                                  int nE, int nt, int nbk,
                                                  const float* __restrict__ W1,
                                                  _Float16* __restrict__ W1t) {
    int tid = threadIdx.x;
    int bx = blockIdx.x;
    if (bx == nt) {  // W1t[n][k] = f16(W1[k][n])
        for (int i = tid; i < HID * INF; i += 1024) {
            int nCol = i >> 6;
            int k = i & 63;
            W1t[i] = (_Float16)W1[k * HID + nCol];
        }
        return;
    }
    __shared__ int hist[1024];
    __shared__ int curs[1024];
    __shared__ int wsum[16];
    hist[tid] = 0;
    __syncthreads();
    int base = bx * TILE_E;
    int d[EPT], s[EPT];
#pragma unroll
    for (int k = 0; k < EPT; ++k) {
        int e = base + k * 1024 + tid;
        if (e < nE) {
            d[k] = dstA[e];
            s[k] = srcA[e];
            atomicAdd(&hist[((unsigned)d[k]) >> BKBITS], 1);
        } else {
            d[k] = -1;
        }
    }
    __syncthreads();
    int lane = tid & 63, wv = tid >> 6;
    int v = hist[tid];
    int own = v;
#pragma unroll
    for (int off = 1; off < 64; off <<= 1) {
        int u = __shfl_up(v, off, 64);
        if (lane >= off) v += u;
    }
    if (lane == 63) wsum[wv] = v;
    __syncthreads();
    for (int g = 0; g < wv; ++g) v += wsum[g];
    int ex = v - own;
    curs[tid] = ex;
    if (tid <= nbk) tileOff[bx * (nbk + 1) + tid] = ex;
    __syncthreads();
#pragma unroll
    for (int k = 0; k < EPT; ++k) {
        if (d[k] >= 0) {
            int bk = ((unsigned)d[k]) >> BKBITS;
            int off = atomicAdd(&curs[bk], 1);
            binned[base + off] =
                ((unsigned)(d[k] & (BKSZ - 1)) << 17) | (unsigned)s[k];
        }
    }
}

// Per-bucket per-node degree -> dinv; fused prescale Xs = f16(dinv*X).
__global__ __launch_bounds__(512) void k_degscale(const unsigned* __restrict__ binned,
                                                  const int* __restrict__ tileOff,
                                                  float* __restrict__ dinv,
                                                  const float4* __restrict__ X4,
                                                  uint4* __restrict__ Xs4,
                                                  int n, int nt, int nbk) {
    __shared__ int segG[NTMAX], segL[NTMAX];
    __shared__ int cnt[BKSZ];
    __shared__ float ddv[BKSZ];
    int tid = threadIdx.x;
    int b = blockIdx.x;
    if (tid < BKSZ) cnt[tid] = 0;
    if (tid < nt) {
        int o0 = tileOff[tid * (nbk + 1) + b];
        int o1 = tileOff[tid * (nbk + 1) + b + 1];
        segG[tid] = tid * TILE_E + o0;
        segL[tid] = o1 - o0;
    }
    __syncthreads();
    int gg = tid >> 4, l16 = tid & 15;  // 32 groups of 16
    for (int t = gg; t < nt; t += 32)
        for (int l = l16; l < segL[t]; l += 16)
            atomicAdd(&cnt[binned[segG[t] + l] >> 17], 1);
    __syncthreads();
    if (tid < BKSZ) {
        float dD = rsqrtf((float)(cnt[tid] + 1));  // +1 self loop
        ddv[tid] = dD;
        int node = (b << BKBITS) + tid;
        if (node < n) dinv[node] = dD;
    }
    __syncthreads();
    // prescale: 128 nodes x 8 chunks
    for (int t2 = tid; t2 < BKSZ * 8; t2 += 512) {
        int nl = t2 >> 3;
        int r2 = t2 & 7;
        int node2 = (b << BKBITS) + nl;
        if (node2 < n) {
            float dD2 = ddv[nl];
            float4 a = X4[(size_t)node2 * 16 + r2 * 2];
            float4 bb = X4[(size_t)node2 * 16 + r2 * 2 + 1];
            __half2 h0 = __float22half2_rn(make_float2(dD2 * a.x, dD2 * a.y));
            __half2 h1 = __float22half2_rn(make_float2(dD2 * a.z, dD2 * a.w));
            __half2 h2 = __float22half2_rn(make_float2(dD2 * bb.x, dD2 * bb.y));
            __half2 h3 = __float22half2_rn(make_float2(dD2 * bb.z, dD2 * bb.w));
            uint4 o;
            o.x = *(unsigned*)&h0; o.y = *(unsigned*)&h1;
            o.z = *(unsigned*)&h2; o.w = *(unsigned*)&h3;
            Xs4[(size_t)node2 * 8 + r2] = o;
        }
    }
}

// Bucket agg via LDS f32 scatter-accumulate + MFMA MLP. 512 thr, 128 nodes.
// LDS: rows 34816 + W1s 16384 + b1/W2 1024 + segs 2112 = 54336 B (<64KB).
__global__ __launch_bounds__(512) void k_agg_mlp_bkt(const uint4* __restrict__ Xs4,
                                                     const unsigned* __restrict__ binned,
                                                     const int* __restrict__ tileOff,
                                                     const float* __restrict__ dinv,
                                                     const uint4* __restrict__ W1t4,
                                                     const float* __restrict__ b1,
                                                     const float* __restrict__ W2,
                                                     float* __restrict__ svs,
                                                     int n, int nt, int nbk) {
    __shared__ float rowsF[BKSZ * RPAD];                     // 34816 B
    __shared__ __align__(16) unsigned short W1s[HID * INF];  // 16 KB swizzled
    __shared__ float b1s[HID], W2s[HID];
    __shared__ int segG[NTMAX], segL[NTMAX];
    int tid = threadIdx.x;
    int b = blockIdx.x;
    const uint2* Xs2 = (const uint2*)Xs4;

    // stage W1t swizzled + b1/W2
    for (int i = tid; i < HID * 8; i += 512) {
        int c = i >> 3, cb = i & 7;
        uint4 v = W1t4[i];
        int off = c * 128 + ((cb * 16) ^ ((c & 7) << 4));
        *(uint4*)((char*)W1s + off) = v;
    }
    if (tid < HID) {
        b1s[tid] = b1[tid];
        W2s[tid] = W2[tid];
    }
    if (tid < nt) {
        int o0 = tileOff[tid * (nbk + 1) + b];
        int o1 = tileOff[tid * (nbk + 1) + b + 1];
        segG[tid] = tid * TILE_E + o0;
        segL[tid] = o1 - o0;
    }
    // init rows with self-loop Xs[node] (f32); zero for padding nodes
    for (int it = tid; it < BKSZ * 8; it += 512) {
        int l = it >> 3, h = it & 7;
        int gn = (b << BKBITS) + l;
        float vals[8] = {0, 0, 0, 0, 0, 0, 0, 0};
        if (gn < n) {
            uint4 v = Xs4[(size_t)gn * 8 + h];
            const __half2* hp = (const __half2*)&v;
#pragma unroll
            for (int i = 0; i < 4; ++i) {
                float2 f = __half22float2(hp[i]);
                vals[2 * i] = f.x;
                vals[2 * i + 1] = f.y;
            }
        }
#pragma unroll
        for (int i = 0; i < 8; ++i) rowsF[l * RPAD + h * 8 + i] = vals[i];
    }
    __syncthreads();
    // accumulate records: 32 groups of 16 lanes; group walks its segments,
    // all 16 lanes broadcast-read the 4B record, each adds an 8B slice.
    int gg = tid >> 4, l16 = tid & 15;
    for (int t = gg; t < nt; t += 32) {
        int L = segL[t], G = segG[t];
        for (int l = 0; l < L; ++l) {
            unsigned u = binned[G + l];  // same addr across group: broadcast
            int dstL = u >> 17;
            int src = u & 0x1FFFF;
            uint2 xv = Xs2[(size_t)src * 16 + l16];
            __half2 p0 = *(__half2*)&xv.x;
            __half2 p1 = *(__half2*)&xv.y;
            float2 f0 = __half22float2(p0);
            float2 f1 = __half22float2(p1);
            float* rp = &rowsF[dstL * RPAD + l16 * 4];
            atomicAdd(rp + 0, f0.x);
            atomicAdd(rp + 1, f0.y);
            atomicAdd(rp + 2, f1.x);
            atomicAdd(rp + 3, f1.y);
        }
    }
    __syncthreads();
    // MFMA phase: 8 waves x 16-node tiles
    int wave = tid >> 6;
    int l = tid & 63;
    int row16 = l & 15;
    int kg = l >> 4;
    int ln = wave * 16 + row16;
    int gn = (b << BKBITS) + ln;
    float dD = (gn < n) ? dinv[gn] : 0.0f;
    half8 a0, a1;
#pragma unroll
    for (int j2 = 0; j2 < 8; ++j2) {
        a0[j2] = (_Float16)(rowsF[ln * RPAD + kg * 8 + j2] * dD);
        a1[j2] = (_Float16)(rowsF[ln * RPAD + 32 + kg * 8 + j2] * dD);
    }
    float p0 = 0.0f, p1 = 0.0f, p2 = 0.0f, p3 = 0.0f;
#pragma unroll
    for (int nt2 = 0; nt2 < 8; ++nt2) {
        int c = nt2 * 16 + row16;
        int swzB = (c & 7) << 4;
        half8 bf0 = *(const half8*)((const char*)W1s + c * 128 + ((kg * 16) ^ swzB));
        half8 bf1 = *(const half8*)((const char*)W1s + c * 128 + ((64 + kg * 16) ^ swzB));
        f32x4 acc4 = {0.0f, 0.0f, 0.0f, 0.0f};
        acc4 = __builtin_amdgcn_mfma_f32_16x16x32_f16(a0, bf0, acc4, 0, 0, 0);
        acc4 = __builtin_amdgcn_mfma_f32_16x16x32_f16(a1, bf1, acc4, 0, 0, 0);
        float b1v = b1s[c];
        float w2v = W2s[c];
        float h;
        h = fmaxf(acc4[0] + b1v, 0.0f); p0 = fmaf(h, w2v, p0);
        h = fmaxf(acc4[1] + b1v, 0.0f); p1 = fmaf(h, w2v, p1);
        h = fmaxf(acc4[2] + b1v, 0.0f); p2 = fmaf(h, w2v, p2);
        h = fmaxf(acc4[3] + b1v, 0.0f); p3 = fmaf(h, w2v, p3);
    }
#pragma unroll
    for (int off = 1; off < 16; off <<= 1) {
        p0 += __shfl_xor(p0, off, 64);
        p1 += __shfl_xor(p1, off, 64);
        p2 += __shfl_xor(p2, off, 64);
        p3 += __shfl_xor(p3, off, 64);
    }
    if (row16 == 0) {
        int nd = (b << BKBITS) + wave * 16 + kg * 4;
        if (nd + 0 < n) svs[nd + 0] = dinv[nd + 0] * p0;
        if (nd + 1 < n) svs[nd + 1] = dinv[nd + 1] * p1;
        if (nd + 2 < n) svs[nd + 2] = dinv[nd + 2] * p2;
        if (nd + 3 < n) svs[nd + 3] = dinv[nd + 3] * p3;
    }
}

// Layer-2 bucket aggregation: p[dstLocal] += svs[src]; out = dD*(p+svs)+b2
__global__ __launch_bounds__(256) void k_out_bkt(const unsigned* __restrict__ binned,
                                                 const int* __restrict__ tileOff,
                                                 const float* __restrict__ dinv,
                                                 const float* __restrict__ svs,
                                                 const float* __restrict__ b2,
                                                 float* __restrict__ out,
                                                 int n, int nt, int nbk) {
    __shared__ int segG[NTMAX], segL[NTMAX];
    __shared__ float pAcc[BKSZ];
    int tid = threadIdx.x;
    int b = blockIdx.x;
    if (tid < BKSZ) pAcc[tid] = 0.0f;
    for (int t = tid; t < nt; t += 256) {
        int o0 = tileOff[t * (nbk + 1) + b];
        int o1 = tileOff[t * (nbk + 1) + b + 1];
        segG[t] = t * TILE_E + o0;
        segL[t] = o1 - o0;
    }
    __syncthreads();
    int gg = tid >> 4, l16 = tid & 15;  // 16 groups of 16
    for (int t = gg; t < nt; t += 16)
        for (int ll = l16; ll < segL[t]; ll += 16) {
            unsigned u = binned[segG[t] + ll];
            atomicAdd(&pAcc[u >> 17], svs[u & 0x1FFFF]);
        }
    __syncthreads();
    if (tid < BKSZ) {
        int node = (b << BKBITS) + tid;
        if (node < n) {
            float dD = dinv[node];
            out[node] = fmaf(dD, pAcc[tid] + svs[node], b2[0]);
        }
    }
}

extern "C" void kernel_launch(void* const* d_in, const int* in_sizes, int n_in,
                              void* d_out, int out_size, void* d_ws, size_t ws_size,
                              hipStream_t stream) {
    const float* X  = (const float*)d_in[0];
    const int*   ei = (const int*)d_in[1];   // int32 (jax x64 disabled)
    const float* W1 = (const float*)d_in[2];
    const float* b1 = (const float*)d_in[3];
    const float* W2 = (const float*)d_in[4];
    const float* b2 = (const float*)d_in[5];

    int N = in_sizes[0] / INF;  // 100000
    int E = in_sizes[1] / 2;    // 1600000
    const int* srcA = ei;
    const int* dstA = ei + E;

    int nt  = (E + TILE_E - 1) / TILE_E;   // 261 tiles
    int nbk = (N + BKSZ - 1) >> BKBITS;    // 782 buckets

    // workspace layout (16B-aligned head first)
    uint4*    Xs4     = (uint4*)d_ws;                      // N*8 = 12.8 MB
    unsigned* binned  = (unsigned*)(Xs4 + (size_t)N * 8);  // nt*TILE_E
    _Float16* W1t     = (_Float16*)(binned + (size_t)nt * TILE_E);  // HID*INF
    int*      tileOff = (int*)(W1t + HID * INF);           // nt*(nbk+1)
    float*    dinv    = (float*)(tileOff + nt * (nbk + 1));// N
    float*    svs     = dinv + N;                          // N
    float*    out     = (float*)d_out;

    k_histbin<<<nt + 1, 1024, 0, stream>>>(srcA, dstA, tileOff, binned, E, nt, nbk,
                                           W1, W1t);
    k_degscale<<<nbk, 512, 0, stream>>>(binned, tileOff, dinv,
                                        (const float4*)X, Xs4, N, nt, nbk);
    k_agg_mlp_bkt<<<nbk, 512, 0, stream>>>(Xs4, binned, tileOff, dinv,
                                           (const uint4*)W1t, b1, W2, svs, N, nt, nbk);
    k_out_bkt<<<nbk, 256, 0, stream>>>(binned, tileOff, dinv, svs, b2, out, N, nt, nbk);
}

// Round 18
// 93.266 us; speedup vs baseline: 7.8027x; 7.8027x over previous
//
#include <hip/hip_runtime.h>
#include <hip/hip_fp16.h>

// GCN 2-layer forward — f16 CSR-gather fused with MFMA MLP. 4 launches:
//  k_histbin: per-tile (8K edges) hist over 196 buckets(512 nodes) + LDS scan
//             -> tileOff; scatter reg-held edges to tile-major binned.
//  k_csr:     per-bucket; global base = sum_t tileOff[t][b] (self-contained);
//             segmented edge reads, counting sort -> rowPtr/dinv/eSrc; fused
//             prescale Xs = f16(dinv*X) of own 512 nodes.
//  k_agg_mlp: 32 nodes/block gather (8 rows in flight) -> swizzled LDS ->
//             16x16x32_f16 MFMA MLP -> svs = dinv*dot(relu(agg@W1+b1),W2).
//  k_out:     scalar CSR gather: out = dD*(sum svs[src]+svs[d]) + b2.
// (R18 = exact revert to the R13 best-known configuration, 93.5 us.)

#define INF 64
#define HID 128
#define BKBITS 9
#define BKSZ 512      // nodes per bucket
#define TILE_E 8192   // edges per tile (1024 thr x 8)
#define TOW 257       // tileOff row width

using half8 = __attribute__((ext_vector_type(8))) _Float16;
using f32x4 = __attribute__((ext_vector_type(4))) float;

// Per-tile histogram + in-LDS scan + scatter. Extra block (bx==nt): W1t prep.
__global__ __launch_bounds__(1024) void k_histbin(const int* __restrict__ srcA,
                                                  const int* __restrict__ dstA,
                                                  int* __restrict__ tileOff,
                                                  unsigned* __restrict__ binned,
                                                  int nE, int nt,
                                                  const float* __restrict__ W1,
                                                  _Float16* __restrict__ W1t) {
    int tid = threadIdx.x;
    int bx = blockIdx.x;
    if (bx == nt) {  // W1t[n][k] = f16(W1[k][n])
        for (int i = tid; i < HID * INF; i += 1024) {
            int nCol = i >> 6;
            int k = i & 63;
            W1t[i] = (_Float16)W1[k * HID + nCol];
        }
        return;
    }
    __shared__ int hist[256];
    __shared__ int curs[256];
    if (tid < 256) hist[tid] = 0;
    __syncthreads();
    int base = bx * TILE_E;
    int d[8], s[8];
#pragma unroll
    for (int k = 0; k < 8; ++k) {
        int e = base + k * 1024 + tid;
        if (e < nE) {
            d[k] = dstA[e];
            s[k] = srcA[e];
            atomicAdd(&hist[((unsigned)d[k]) >> BKBITS], 1);
        } else {
            d[k] = -1;
        }
    }
    __syncthreads();
    int own = (tid < 256) ? hist[tid] : 0;
    for (int off = 1; off < 256; off <<= 1) {  // inclusive scan, 8 rounds
        int u = (tid < 256 && tid >= off) ? hist[tid - off] : 0;
        __syncthreads();
        if (tid < 256) hist[tid] += u;
        __syncthreads();
    }
    if (tid < 256) {
        int ex = hist[tid] - own;
        curs[tid] = ex;
        tileOff[bx * TOW + tid] = ex;
        if (tid == 255) tileOff[bx * TOW + 256] = hist[255];  // tile total
    }
    __syncthreads();
#pragma unroll
    for (int k = 0; k < 8; ++k) {
        if (d[k] >= 0) {
            int bk = ((unsigned)d[k]) >> BKBITS;
            int off = atomicAdd(&curs[bk], 1);
            binned[base + off] = ((unsigned)(d[k] & (BKSZ - 1)) << 17) | (unsigned)s[k];
        }
    }
}

// Per-bucket counting sort + fused prescale. Self-contained global base.
__global__ __launch_bounds__(1024) void k_csr(const unsigned* __restrict__ binned,
                                              const int* __restrict__ tileOff,
                                              int* __restrict__ rowPtr,
                                              float* __restrict__ dinv,
                                              int* __restrict__ eSrc,
                                              const float4* __restrict__ X4,
                                              uint4* __restrict__ Xs4,
                                              int n, int nt, int nbk) {
    __shared__ int segS[256], segL[256];
    __shared__ int hist[512];
    __shared__ int curs[512];
    __shared__ float ddv[512];
    __shared__ int bBaseS;
    int tid = threadIdx.x;
    int b = blockIdx.x;
    if (tid == 0) bBaseS = 0;
    if (tid < 512) hist[tid] = 0;
    __syncthreads();
    if (tid < nt) {
        int o0 = tileOff[tid * TOW + b];
        int o1 = tileOff[tid * TOW + b + 1];
        segS[tid] = tid * TILE_E + o0;
        segL[tid] = o1 - o0;
        atomicAdd(&bBaseS, o0);  // sum of per-tile excl prefixes = global base
    }
    __syncthreads();
    int w = tid >> 6, lane = tid & 63;
    for (int t = w; t < nt; t += 16)
        for (int l = lane; l < segL[t]; l += 64)
            atomicAdd(&hist[binned[segS[t] + l] >> 17], 1);
    __syncthreads();
    int own = (tid < 512) ? hist[tid] : 0;
    for (int off = 1; off < 512; off <<= 1) {  // inclusive scan, 9 rounds
        int u = (tid < 512 && tid >= off) ? hist[tid - off] : 0;
        __syncthreads();
        if (tid < 512) hist[tid] += u;
        __syncthreads();
    }
    int bBase = bBaseS;
    if (tid < 512) {
        int pos0 = bBase + hist[tid] - own;
        curs[tid] = pos0;
        float dD = rsqrtf((float)(own + 1));  // +1 self loop
        ddv[tid] = dD;
        int node = (b << BKBITS) + tid;
        if (node < n) {
            rowPtr[node] = pos0;
            dinv[node] = dD;
        }
        if (b == nbk - 1 && tid == 511) rowPtr[n] = bBase + hist[511];
    }
    __syncthreads();
    for (int t = w; t < nt; t += 16)
        for (int l = lane; l < segL[t]; l += 64) {
            unsigned v = binned[segS[t] + l];
            int pos = atomicAdd(&curs[v >> 17], 1);
            eSrc[pos] = (int)(v & 0x1FFFFu);
        }
    // fused prescale of this bucket's nodes (ddv synced by earlier barrier)
    int nbase = b << BKBITS;
#pragma unroll
    for (int k2 = 0; k2 < 4; ++k2) {
        int t2 = k2 * 1024 + tid;
        int nl = t2 >> 3;
        int r2 = t2 & 7;
        int node2 = nbase + nl;
        if (node2 < n) {
            float dD2 = ddv[nl];
            float4 a = X4[(size_t)node2 * 16 + r2 * 2];
            float4 bb = X4[(size_t)node2 * 16 + r2 * 2 + 1];
            __half2 h0 = __float22half2_rn(make_float2(dD2 * a.x, dD2 * a.y));
            __half2 h1 = __float22half2_rn(make_float2(dD2 * a.z, dD2 * a.w));
            __half2 h2 = __float22half2_rn(make_float2(dD2 * bb.x, dD2 * bb.y));
            __half2 h3 = __float22half2_rn(make_float2(dD2 * bb.z, dD2 * bb.w));
            uint4 o;
            o.x = *(unsigned*)&h0; o.y = *(unsigned*)&h1;
            o.z = *(unsigned*)&h2; o.w = *(unsigned*)&h3;
            Xs4[(size_t)node2 * 8 + r2] = o;
        }
    }
}

__device__ inline void acc8_add(const uint4& v, float* acc) {
    const __half2* hp = (const __half2*)&v;
#pragma unroll
    for (int i = 0; i < 4; ++i) {
        float2 f = __half22float2(hp[i]);
        acc[2 * i]     += f.x;
        acc[2 * i + 1] += f.y;
    }
}

// Fused gather + MFMA MLP. 256 thr = 32 nodes/block.
// Phase 1: 8 lanes/node gather agg row (f32 acc, 8 rows in flight) ->
//          f16 row in swizzled LDS.
// Phase 2: waves 0-1 each run one 16-node MFMA tile (8 N-tiles x 2 K-steps),
//          A/B frags from LDS; epilogue bias+relu+W2-dot; svs = dinv*result.
__global__ __launch_bounds__(256) void k_agg_mlp(const uint4* __restrict__ Xs4,
                                                 const int* __restrict__ rowPtr,
                                                 const int* __restrict__ eSrc,
                                                 const float* __restrict__ dinv,
                                                 const uint4* __restrict__ W1t4,
                                                 const float* __restrict__ b1,
                                                 const float* __restrict__ W2,
                                                 float* __restrict__ svs, int n) {
    __shared__ __align__(16) unsigned short W1s[HID * INF];  // 16 KB swizzled
    __shared__ __align__(16) unsigned short aggS[32 * INF];  // 4 KB swizzled
    __shared__ float b1s[HID];
    __shared__ float W2s[HID];
    int tid = threadIdx.x;

    // phase 0: stage W1t into swizzled LDS (+ bias/W2)
    for (int i = tid; i < HID * 8; i += 256) {   // 1024 uint4 chunks
        int c = i >> 3, cb = i & 7;
        uint4 v = W1t4[i];
        int off = c * 128 + ((cb * 16) ^ ((c & 7) << 4));
        *(uint4*)((char*)W1s + off) = v;
    }
    if (tid < HID) {
        b1s[tid] = b1[tid];
        W2s[tid] = W2[tid];
    }

    // phase 1: gather
    int node0 = blockIdx.x * 32;
    int w = tid >> 3;   // local node 0..31
    int r = tid & 7;    // 16B chunk of the 128B row
    int node = node0 + w;
    if (node < n) {
        int beg = rowPtr[node];
        int end = rowPtr[node + 1];
        float dD = dinv[node];
        float acc[8];
        {   // self-loop init
            uint4 v = Xs4[(size_t)node * 8 + r];
            const __half2* hp = (const __half2*)&v;
#pragma unroll
            for (int i = 0; i < 4; ++i) {
                float2 f = __half22float2(hp[i]);
                acc[2 * i] = f.x;
                acc[2 * i + 1] = f.y;
            }
        }
        int j = beg;
        int aEnd = min(end, (beg + 3) & ~3);
        for (; j < aEnd; ++j) {
            uint4 v = Xs4[(size_t)eSrc[j] * 8 + r];
            acc8_add(v, acc);
        }
        for (; j + 7 < end; j += 8) {   // 8 rows in flight
            int4 sa = *(const int4*)(eSrc + j);
            int4 sb = *(const int4*)(eSrc + j + 4);
            uint4 v0 = Xs4[(size_t)sa.x * 8 + r];
            uint4 v1 = Xs4[(size_t)sa.y * 8 + r];
            uint4 v2 = Xs4[(size_t)sa.z * 8 + r];
            uint4 v3 = Xs4[(size_t)sa.w * 8 + r];
            uint4 v4 = Xs4[(size_t)sb.x * 8 + r];
            uint4 v5 = Xs4[(size_t)sb.y * 8 + r];
            uint4 v6 = Xs4[(size_t)sb.z * 8 + r];
            uint4 v7 = Xs4[(size_t)sb.w * 8 + r];
            acc8_add(v0, acc); acc8_add(v1, acc); acc8_add(v2, acc); acc8_add(v3, acc);
            acc8_add(v4, acc); acc8_add(v5, acc); acc8_add(v6, acc); acc8_add(v7, acc);
        }
        if (j + 3 < end) {
            int4 s4 = *(const int4*)(eSrc + j);
            uint4 v0 = Xs4[(size_t)s4.x * 8 + r];
            uint4 v1 = Xs4[(size_t)s4.y * 8 + r];
            uint4 v2 = Xs4[(size_t)s4.z * 8 + r];
            uint4 v3 = Xs4[(size_t)s4.w * 8 + r];
            acc8_add(v0, acc); acc8_add(v1, acc); acc8_add(v2, acc); acc8_add(v3, acc);
            j += 4;
        }
        for (; j < end; ++j) {
            uint4 v = Xs4[(size_t)eSrc[j] * 8 + r];
            acc8_add(v, acc);
        }
        __half2 h0 = __float22half2_rn(make_float2(dD * acc[0], dD * acc[1]));
        __half2 h1 = __float22half2_rn(make_float2(dD * acc[2], dD * acc[3]));
        __half2 h2 = __float22half2_rn(make_float2(dD * acc[4], dD * acc[5]));
        __half2 h3 = __float22half2_rn(make_float2(dD * acc[6], dD * acc[7]));
        uint4 o;
        o.x = *(unsigned*)&h0; o.y = *(unsigned*)&h1;
        o.z = *(unsigned*)&h2; o.w = *(unsigned*)&h3;
        int off = w * 128 + ((r * 16) ^ ((w & 7) << 4));
        *(uint4*)((char*)aggS + off) = o;
    }
    __syncthreads();

    // phase 2: MFMA (waves 0-1)
    int wave = tid >> 6;
    if (wave < 2) {
        int l = tid & 63;
        int row16 = l & 15;
        int kg = l >> 4;
        int lrow = wave * 16 + row16;
        int swzA = (lrow & 7) << 4;
        half8 a0 = *(const half8*)((const char*)aggS + lrow * 128 + ((kg * 16) ^ swzA));
        half8 a1 = *(const half8*)((const char*)aggS + lrow * 128 + ((64 + kg * 16) ^ swzA));
        float p0 = 0.0f, p1 = 0.0f, p2 = 0.0f, p3 = 0.0f;
#pragma unroll
        for (int nt = 0; nt < 8; ++nt) {
            int c = nt * 16 + row16;
            int swzB = (c & 7) << 4;
            half8 bf0 = *(const half8*)((const char*)W1s + c * 128 + ((kg * 16) ^ swzB));
            half8 bf1 = *(const half8*)((const char*)W1s + c * 128 + ((64 + kg * 16) ^ swzB));
            f32x4 acc4 = {0.0f, 0.0f, 0.0f, 0.0f};
            acc4 = __builtin_amdgcn_mfma_f32_16x16x32_f16(a0, bf0, acc4, 0, 0, 0);
            acc4 = __builtin_amdgcn_mfma_f32_16x16x32_f16(a1, bf1, acc4, 0, 0, 0);
            float b1v = b1s[c];
            float w2v = W2s[c];
            float h;
            h = fmaxf(acc4[0] + b1v, 0.0f); p0 = fmaf(h, w2v, p0);
            h = fmaxf(acc4[1] + b1v, 0.0f); p1 = fmaf(h, w2v, p1);
            h = fmaxf(acc4[2] + b1v, 0.0f); p2 = fmaf(h, w2v, p2);
            h = fmaxf(acc4[3] + b1v, 0.0f); p3 = fmaf(h, w2v, p3);
        }
#pragma unroll
        for (int off = 1; off < 16; off <<= 1) {
            p0 += __shfl_xor(p0, off, 64);
            p1 += __shfl_xor(p1, off, 64);
            p2 += __shfl_xor(p2, off, 64);
            p3 += __shfl_xor(p3, off, 64);
        }
        if (row16 == 0) {
            int nd = node0 + wave * 16 + kg * 4;
            if (nd + 0 < n) svs[nd + 0] = dinv[nd + 0] * p0;
            if (nd + 1 < n) svs[nd + 1] = dinv[nd + 1] * p1;
            if (nd + 2 < n) svs[nd + 2] = dinv[nd + 2] * p2;
            if (nd + 3 < n) svs[nd + 3] = dinv[nd + 3] * p3;
        }
    }
}

// 4 nodes per wave: out[d] = dD*(sum svs[src] + svs[d]) + b2
__global__ __launch_bounds__(256) void k_out(const int* __restrict__ rowPtr,
                                             const int* __restrict__ eSrc,
                                             const float* __restrict__ dinv,
                                             const float* __restrict__ svs,
                                             const float* __restrict__ b2,
                                             float* __restrict__ out, int n) {
    int t = blockIdx.x * blockDim.x + threadIdx.x;
    int node = t >> 4;
    int r = t & 15;
    if (node >= n) return;
    int beg = rowPtr[node];
    int end = rowPtr[node + 1];
    float p = 0.0f;
    for (int j = beg + r; j < end; j += 16) p += svs[eSrc[j]];
    p += __shfl_xor(p, 1, 16);
    p += __shfl_xor(p, 2, 16);
    p += __shfl_xor(p, 4, 16);
    p += __shfl_xor(p, 8, 16);
    if (r == 0) {
        float dD = dinv[node];
        out[node] = fmaf(dD, p + svs[node], b2[0]);
    }
}

extern "C" void kernel_launch(void* const* d_in, const int* in_sizes, int n_in,
                              void* d_out, int out_size, void* d_ws, size_t ws_size,
                              hipStream_t stream) {
    const float* X  = (const float*)d_in[0];
    const int*   ei = (const int*)d_in[1];   // int32 (jax x64 disabled)
    const float* W1 = (const float*)d_in[2];
    const float* b1 = (const float*)d_in[3];
    const float* W2 = (const float*)d_in[4];
    const float* b2 = (const float*)d_in[5];

    int N = in_sizes[0] / INF;  // 100000
    int E = in_sizes[1] / 2;    // 1600000
    const int* srcA = ei;
    const int* dstA = ei + E;

    int nt  = (E + TILE_E - 1) / TILE_E;       // 196 tiles
    int nbk = (N + BKSZ - 1) >> BKBITS;        // 196 buckets

    // workspace layout (16B-aligned head first)
    uint4*    Xs4      = (uint4*)d_ws;                     // N*8 = 12.8 MB
    unsigned* binned   = (unsigned*)(Xs4 + (size_t)N * 8); // nt*TILE_E
    int*      eSrc     = (int*)(binned + (size_t)nt * TILE_E);  // E
    _Float16* W1t      = (_Float16*)(eSrc + E);            // HID*INF
    int*      tileOff  = (int*)(W1t + HID * INF);          // nt*TOW
    int*      rowPtr   = tileOff + nt * TOW;               // N+1
    float*    dinv     = (float*)(rowPtr + N + 1);         // N
    float*    svs      = dinv + N;                         // N
    float*    out      = (float*)d_out;

    k_histbin<<<nt + 1, 1024, 0, stream>>>(srcA, dstA, tileOff, binned, E, nt, W1, W1t);
    k_csr<<<nbk, 1024, 0, stream>>>(binned, tileOff, rowPtr, dinv, eSrc,
                                    (const float4*)X, Xs4, N, nt, nbk);
    k_agg_mlp<<<(N + 31) / 32, 256, 0, stream>>>(Xs4, rowPtr, eSrc, dinv,
                                                 (const uint4*)W1t, b1, W2, svs, N);
    k_out<<<(N * 16 + 255) / 256, 256, 0, stream>>>(rowPtr, eSrc, dinv, svs, b2, out, N);
}